// Round 1
// baseline (576.936 us; speedup 1.0000x reference)
//
#include <hip/hip_runtime.h>

#define Bb 8
#define Cc 64
#define Oo 64
#define Hh 96
#define Ww 96
#define HW 9216
#define K2 9
#define NOFF 18

// ws layout (floats):
//   offs : Bb*HW*NOFF = 1,327,104   (layout [b,h,w,18])
//   x_t  : Bb*HW*Cc   = 4,718,592   (layout [b,h,w,c])
//   w_t  : Cc*K2*Oo   =    36,864   (layout [c,k,o])
#define OFFS_SZ (Bb*HW*NOFF)
#define XT_SZ   (Bb*HW*Cc)
#define WT_SZ   (Cc*K2*Oo)

// ---------------- x transpose: (b,c,h,w) -> (b,hw,c) ----------------
__global__ void xpose_kernel(const float* __restrict__ x, float* __restrict__ xt) {
    __shared__ float tile[64][65];
    int bid  = blockIdx.x;            // 0..1151
    int b    = bid / 144;
    int t0   = (bid % 144) * 64;      // hw tile offset
    int lane = threadIdx.x & 63;
    int sub  = threadIdx.x >> 6;      // 0..3
    const float* xb = x + (size_t)b * Cc * HW;
    #pragma unroll
    for (int i = 0; i < 16; ++i) {
        int c = sub * 16 + i;
        tile[c][lane] = xb[c * HW + t0 + lane];      // coalesced over hw
    }
    __syncthreads();
    float* xtb = xt + ((size_t)b * HW + t0) * Cc;
    #pragma unroll
    for (int i = 0; i < 16; ++i) {
        int hw = sub * 16 + i;
        xtb[hw * Cc + lane] = tile[lane][hw];        // coalesced over c
    }
}

// ---------------- weight transpose: (o,c,3,3) -> (c*9+k, o) ----------------
__global__ void wt_kernel(const float* __restrict__ cw, float* __restrict__ wt) {
    int idx = blockIdx.x * 256 + threadIdx.x;   // 0..36863
    int o   = idx & 63;
    int ck  = idx >> 6;                         // c*9+k
    wt[idx] = cw[o * 576 + ck];                 // coalesced writes
}

// ---------------- offset conv: 18ch 3x3 conv over 64 in-ch ----------------
// thread per pixel, 16-channel chunk per block-group, atomic accumulate
__global__ void offconv_kernel(const float* __restrict__ x, const float* __restrict__ ow,
                               const float* __restrict__ ob, float* __restrict__ offs) {
    int chunk = blockIdx.x / 288;                          // 0..3 -> c chunk
    int pixid = (blockIdx.x % 288) * 256 + threadIdx.x;    // 0..73727
    int b = pixid / HW;
    int hw = pixid % HW;
    int h = hw / Ww, w = hw % Ww;
    int cs = chunk * 16;

    float acc[NOFF];
    #pragma unroll
    for (int oc = 0; oc < NOFF; ++oc) acc[oc] = (chunk == 0) ? ob[oc] : 0.f;

    const float* xb = x + (size_t)b * Cc * HW;
    for (int ci = 0; ci < 16; ++ci) {
        int c = cs + ci;
        float xv[9];
        #pragma unroll
        for (int ky = 0; ky < 3; ++ky) {
            #pragma unroll
            for (int kx = 0; kx < 3; ++kx) {
                int y = h - 1 + ky, xx = w - 1 + kx;
                bool v = (y >= 0) && (y < Hh) && (xx >= 0) && (xx < Ww);
                xv[ky*3+kx] = v ? xb[c * HW + y * Ww + xx] : 0.f;
            }
        }
        const float* wp = ow + c * 9;   // weight ow[oc*576 + c*9 + t], uniform -> s_load
        #pragma unroll
        for (int oc = 0; oc < NOFF; ++oc) {
            #pragma unroll
            for (int t = 0; t < 9; ++t) acc[oc] += xv[t] * wp[oc * 576 + t];
        }
    }
    float* op = offs + (size_t)pixid * NOFF;
    #pragma unroll
    for (int oc = 0; oc < NOFF; ++oc) atomicAdd(op + oc, acc[oc]);
}

// ---------------- deformable conv ----------------
// block = 256 threads, 8 pixels (consecutive w). Phase A: bilinear tables.
// Phase B: gather samples -> LDS s[pix][c][k(pad 12)]. Phase C: lane=o GEMM.
__global__ void deform_kernel(const float* __restrict__ xt, const float* __restrict__ offs,
                              const float* __restrict__ wt, const float* __restrict__ cb,
                              float* __restrict__ out) {
    __shared__ float offbuf[144];        // 8 pix * 18
    __shared__ int   tbase[72 * 4];      // 8 pix * 9 k * 4 corners (clamped base addr)
    __shared__ float twgt[72 * 4];       // bilinear weights premultiplied by validity
    __shared__ float s[8 * 64 * 12];     // sample tile, k padded to 12 (16B aligned rows)

    int bid = blockIdx.x;                // 9216 blocks
    int b  = bid / 1152;
    int r  = bid % 1152;
    int h  = r / 12;
    int w0 = (r % 12) * 8;
    int tid = threadIdx.x;

    if (tid < 144) offbuf[tid] = offs[((size_t)b * HW + h * Ww + w0) * NOFF + tid];
    __syncthreads();

    if (tid < 72) {
        int pix = tid / 9, k = tid % 9;
        int ky = k / 3, kx = k % 3;
        float dy = offbuf[pix * NOFF + 2 * k];
        float dx = offbuf[pix * NOFF + 2 * k + 1];
        float py = (float)(h - 1 + ky) + dy;
        float px = (float)(w0 + pix - 1 + kx) + dx;
        float fy = floorf(py), fx = floorf(px);
        int y0 = (int)fy, x0 = (int)fx;
        float wy = py - fy, wx = px - fx;
        int y1 = y0 + 1, x1 = x0 + 1;
        bool vy0 = (y0 >= 0) && (y0 < Hh), vy1 = (y1 >= 0) && (y1 < Hh);
        bool vx0 = (x0 >= 0) && (x0 < Ww), vx1 = (x1 >= 0) && (x1 < Ww);
        int y0c = min(max(y0, 0), Hh - 1), y1c = min(max(y1, 0), Hh - 1);
        int x0c = min(max(x0, 0), Ww - 1), x1c = min(max(x1, 0), Ww - 1);
        int base = b * HW;
        tbase[tid * 4 + 0] = (base + y0c * Ww + x0c) * Cc;
        tbase[tid * 4 + 1] = (base + y0c * Ww + x1c) * Cc;
        tbase[tid * 4 + 2] = (base + y1c * Ww + x0c) * Cc;
        tbase[tid * 4 + 3] = (base + y1c * Ww + x1c) * Cc;
        twgt[tid * 4 + 0] = (1.f - wy) * (1.f - wx) * ((vy0 && vx0) ? 1.f : 0.f);
        twgt[tid * 4 + 1] = (1.f - wy) * wx         * ((vy0 && vx1) ? 1.f : 0.f);
        twgt[tid * 4 + 2] = wy * (1.f - wx)         * ((vy1 && vx0) ? 1.f : 0.f);
        twgt[tid * 4 + 3] = wy * wx                 * ((vy1 && vx1) ? 1.f : 0.f);
    }
    __syncthreads();

    {   // Phase B: gather. lane = c, wave q handles pixels {2q, 2q+1}
        int c = tid & 63, q = tid >> 6;
        #pragma unroll
        for (int pp = 0; pp < 2; ++pp) {
            int pix = q * 2 + pp;
            #pragma unroll
            for (int k = 0; k < 9; ++k) {
                int t = pix * 9 + k;
                float v = xt[tbase[t*4+0] + c] * twgt[t*4+0]
                        + xt[tbase[t*4+1] + c] * twgt[t*4+1]
                        + xt[tbase[t*4+2] + c] * twgt[t*4+2]
                        + xt[tbase[t*4+3] + c] * twgt[t*4+3];
                s[(pix * 64 + c) * 12 + k] = v;
            }
        }
    }
    __syncthreads();

    {   // Phase C: lane = o, wave q accumulates pixels {2q, 2q+1}
        int o = tid & 63, q = tid >> 6;
        int pix0 = q * 2;
        float acc0 = cb[o], acc1 = acc0;
        for (int c = 0; c < 64; ++c) {
            const float* sp0 = &s[(pix0 * 64 + c) * 12];
            const float* sp1 = &s[((pix0 + 1) * 64 + c) * 12];
            const float* wp  = &wt[(c * 9) * 64 + o];
            #pragma unroll
            for (int k = 0; k < 9; ++k) {
                float wv = wp[k * 64];          // coalesced over o
                acc0 += sp0[k] * wv;            // LDS broadcast
                acc1 += sp1[k] * wv;
            }
        }
        size_t ob = ((size_t)b * Oo + o) * HW + (size_t)h * Ww + w0 + pix0;
        out[ob]     = acc0;
        out[ob + 1] = acc1;
    }
}

extern "C" void kernel_launch(void* const* d_in, const int* in_sizes, int n_in,
                              void* d_out, int out_size, void* d_ws, size_t ws_size,
                              hipStream_t stream) {
    const float* x  = (const float*)d_in[0];
    const float* ow = (const float*)d_in[1];
    const float* ob = (const float*)d_in[2];
    const float* cw = (const float*)d_in[3];
    const float* cb = (const float*)d_in[4];
    float* out = (float*)d_out;

    float* offs = (float*)d_ws;
    float* xt   = offs + OFFS_SZ;
    float* wt   = xt + XT_SZ;

    hipMemsetAsync(offs, 0, OFFS_SZ * sizeof(float), stream);
    xpose_kernel  <<<1152, 256, 0, stream>>>(x, xt);
    wt_kernel     <<<144,  256, 0, stream>>>(cw, wt);
    offconv_kernel<<<1152, 256, 0, stream>>>(x, ow, ob, offs);
    deform_kernel <<<9216, 256, 0, stream>>>(xt, offs, wt, cb, out);
}

// Round 2
// 367.884 us; speedup vs baseline: 1.5683x; 1.5683x over previous
//
#include <hip/hip_runtime.h>

#define Bb 8
#define Cc 64
#define Oo 64
#define Hh 96
#define Ww 96
#define HW 9216
#define K2 9
#define NOFF 18

// ws layout (floats):
//   offs : Bb*NOFF*HW = 1,327,104   (layout [b][18][hw])
//   x_t  : Bb*HW*Cc   = 4,718,592   (layout [b,h,w,c])
//   w_t  : Cc*K2*Oo   =    36,864   (layout [c,k,o])
#define OFFS_SZ (Bb*NOFF*HW)
#define XT_SZ   (Bb*HW*Cc)
#define WT_SZ   (Cc*K2*Oo)

// ---------------- x transpose: (b,c,h,w) -> (b,hw,c) ----------------
__global__ void xpose_kernel(const float* __restrict__ x, float* __restrict__ xt) {
    __shared__ float tile[64][65];
    int bid  = blockIdx.x;            // 0..1151
    int b    = bid / 144;
    int t0   = (bid % 144) * 64;      // hw tile offset
    int lane = threadIdx.x & 63;
    int sub  = threadIdx.x >> 6;      // 0..3
    const float* xb = x + (size_t)b * Cc * HW;
    #pragma unroll
    for (int i = 0; i < 16; ++i) {
        int c = sub * 16 + i;
        tile[c][lane] = xb[c * HW + t0 + lane];      // coalesced over hw
    }
    __syncthreads();
    float* xtb = xt + ((size_t)b * HW + t0) * Cc;
    #pragma unroll
    for (int i = 0; i < 16; ++i) {
        int hw = sub * 16 + i;
        xtb[hw * Cc + lane] = tile[lane][hw];        // coalesced over c
    }
}

// ---------------- weight transpose: (o,c,3,3) -> (c*9+k, o) ----------------
__global__ void wt_kernel(const float* __restrict__ cw, float* __restrict__ wt) {
    int idx = blockIdx.x * 256 + threadIdx.x;   // 0..36863
    int o   = idx & 63;
    int ck  = idx >> 6;                         // c*9+k
    wt[idx] = cw[o * 576 + ck];                 // coalesced writes
}

// ---------------- offset conv: 18ch 3x3 conv over 64 in-ch ----------------
// block = 256 thr = 64 pixels x 4 c-chunk waves; register accumulate,
// LDS cross-wave reduce, no atomics. offs layout [b][18][hw].
__global__ void offconv_kernel(const float* __restrict__ x, const float* __restrict__ ow,
                               const float* __restrict__ ob, float* __restrict__ offs) {
    __shared__ float red[3][64 * NOFF];    // chunks 1..3 park partials here

    int bid   = blockIdx.x;                 // 0..1151
    int b     = bid / 144;
    int t0    = (bid % 144) * 64;           // 64 consecutive hw within batch b
    int lane  = threadIdx.x & 63;
    int chunk = threadIdx.x >> 6;           // wave-uniform: c in [chunk*16, +16)

    int hw = t0 + lane;
    int h  = hw / Ww, w = hw % Ww;

    float acc[NOFF];
    #pragma unroll
    for (int oc = 0; oc < NOFF; ++oc) acc[oc] = 0.f;

    const float* xb = x + (size_t)b * Cc * HW;
    int cs = chunk * 16;
    for (int ci = 0; ci < 16; ++ci) {
        int c = cs + ci;
        float xv[9];
        #pragma unroll
        for (int ky = 0; ky < 3; ++ky) {
            #pragma unroll
            for (int kx = 0; kx < 3; ++kx) {
                int y = h - 1 + ky, xx = w - 1 + kx;
                bool v = (y >= 0) && (y < Hh) && (xx >= 0) && (xx < Ww);
                xv[ky*3+kx] = v ? xb[c * HW + y * Ww + xx] : 0.f;
            }
        }
        const float* wp = ow + c * 9;       // wave-uniform -> s_load
        #pragma unroll
        for (int oc = 0; oc < NOFF; ++oc) {
            #pragma unroll
            for (int t = 0; t < 9; ++t) acc[oc] += xv[t] * wp[oc * 576 + t];
        }
    }

    if (chunk > 0) {
        #pragma unroll
        for (int oc = 0; oc < NOFF; ++oc) red[chunk - 1][lane * NOFF + oc] = acc[oc];
    }
    __syncthreads();
    if (chunk == 0) {
        #pragma unroll
        for (int oc = 0; oc < NOFF; ++oc) {
            float tot = acc[oc] + ob[oc]
                      + red[0][lane * NOFF + oc]
                      + red[1][lane * NOFF + oc]
                      + red[2][lane * NOFF + oc];
            offs[((size_t)b * NOFF + oc) * HW + hw] = tot;   // coalesced over lane
        }
    }
}

// ---------------- deformable conv ----------------
// block = 256 threads, 8 pixels (consecutive w). Phase A: bilinear tables.
// Phase B: gather samples -> LDS s[pix][c][k(pad 12)]. Phase C: lane=o GEMM.
__global__ void deform_kernel(const float* __restrict__ xt, const float* __restrict__ offs,
                              const float* __restrict__ wt, const float* __restrict__ cb,
                              float* __restrict__ out) {
    __shared__ float offbuf[144];        // 8 pix * 18
    __shared__ int   tbase[72 * 4];      // 8 pix * 9 k * 4 corners (clamped base addr)
    __shared__ float twgt[72 * 4];       // bilinear weights premultiplied by validity
    __shared__ float s[8 * 64 * 12];     // sample tile, k padded to 12 (16B aligned rows)

    int bid = blockIdx.x;                // 9216 blocks
    int b  = bid / 1152;
    int r  = bid % 1152;
    int h  = r / 12;
    int w0 = (r % 12) * 8;
    int tid = threadIdx.x;

    if (tid < 144) {
        int pix = tid & 7, oc = tid >> 3;   // offs layout [b][18][hw]
        offbuf[pix * NOFF + oc] =
            offs[((size_t)b * NOFF + oc) * HW + h * Ww + w0 + pix];
    }
    __syncthreads();

    if (tid < 72) {
        int pix = tid / 9, k = tid % 9;
        int ky = k / 3, kx = k % 3;
        float dy = offbuf[pix * NOFF + 2 * k];
        float dx = offbuf[pix * NOFF + 2 * k + 1];
        float py = (float)(h - 1 + ky) + dy;
        float px = (float)(w0 + pix - 1 + kx) + dx;
        float fy = floorf(py), fx = floorf(px);
        int y0 = (int)fy, x0 = (int)fx;
        float wy = py - fy, wx = px - fx;
        int y1 = y0 + 1, x1 = x0 + 1;
        bool vy0 = (y0 >= 0) && (y0 < Hh), vy1 = (y1 >= 0) && (y1 < Hh);
        bool vx0 = (x0 >= 0) && (x0 < Ww), vx1 = (x1 >= 0) && (x1 < Ww);
        int y0c = min(max(y0, 0), Hh - 1), y1c = min(max(y1, 0), Hh - 1);
        int x0c = min(max(x0, 0), Ww - 1), x1c = min(max(x1, 0), Ww - 1);
        int base = b * HW;
        tbase[tid * 4 + 0] = (base + y0c * Ww + x0c) * Cc;
        tbase[tid * 4 + 1] = (base + y0c * Ww + x1c) * Cc;
        tbase[tid * 4 + 2] = (base + y1c * Ww + x0c) * Cc;
        tbase[tid * 4 + 3] = (base + y1c * Ww + x1c) * Cc;
        twgt[tid * 4 + 0] = (1.f - wy) * (1.f - wx) * ((vy0 && vx0) ? 1.f : 0.f);
        twgt[tid * 4 + 1] = (1.f - wy) * wx         * ((vy0 && vx1) ? 1.f : 0.f);
        twgt[tid * 4 + 2] = wy * (1.f - wx)         * ((vy1 && vx0) ? 1.f : 0.f);
        twgt[tid * 4 + 3] = wy * wx                 * ((vy1 && vx1) ? 1.f : 0.f);
    }
    __syncthreads();

    {   // Phase B: gather. lane = c, wave q handles pixels {2q, 2q+1}
        int c = tid & 63, q = tid >> 6;
        #pragma unroll
        for (int pp = 0; pp < 2; ++pp) {
            int pix = q * 2 + pp;
            #pragma unroll
            for (int k = 0; k < 9; ++k) {
                int t = pix * 9 + k;
                float v = xt[tbase[t*4+0] + c] * twgt[t*4+0]
                        + xt[tbase[t*4+1] + c] * twgt[t*4+1]
                        + xt[tbase[t*4+2] + c] * twgt[t*4+2]
                        + xt[tbase[t*4+3] + c] * twgt[t*4+3];
                s[(pix * 64 + c) * 12 + k] = v;
            }
        }
    }
    __syncthreads();

    {   // Phase C: lane = o, wave q accumulates pixels {2q, 2q+1}
        int o = tid & 63, q = tid >> 6;
        int pix0 = q * 2;
        float acc0 = cb[o], acc1 = acc0;
        for (int c = 0; c < 64; ++c) {
            const float* sp0 = &s[(pix0 * 64 + c) * 12];
            const float* sp1 = &s[((pix0 + 1) * 64 + c) * 12];
            const float* wp  = &wt[(c * 9) * 64 + o];
            #pragma unroll
            for (int k = 0; k < 9; ++k) {
                float wv = wp[k * 64];          // coalesced over o
                acc0 += sp0[k] * wv;            // LDS broadcast
                acc1 += sp1[k] * wv;
            }
        }
        size_t ob = ((size_t)b * Oo + o) * HW + (size_t)h * Ww + w0 + pix0;
        out[ob]     = acc0;
        out[ob + 1] = acc1;
    }
}

extern "C" void kernel_launch(void* const* d_in, const int* in_sizes, int n_in,
                              void* d_out, int out_size, void* d_ws, size_t ws_size,
                              hipStream_t stream) {
    const float* x  = (const float*)d_in[0];
    const float* ow = (const float*)d_in[1];
    const float* ob = (const float*)d_in[2];
    const float* cw = (const float*)d_in[3];
    const float* cb = (const float*)d_in[4];
    float* out = (float*)d_out;

    float* offs = (float*)d_ws;
    float* xt   = offs + OFFS_SZ;
    float* wt   = xt + XT_SZ;

    xpose_kernel  <<<1152, 256, 0, stream>>>(x, xt);
    wt_kernel     <<<144,  256, 0, stream>>>(cw, wt);
    offconv_kernel<<<1152, 256, 0, stream>>>(x, ow, ob, offs);
    deform_kernel <<<9216, 256, 0, stream>>>(xt, offs, wt, cb, out);
}

// Round 3
// 154.519 us; speedup vs baseline: 3.7338x; 2.3808x over previous
//
#include <hip/hip_runtime.h>

#define Bb 8
#define Cc 64
#define Oo 64
#define Hh 96
#define Ww 96
#define HW 9216
#define NOFF 18

typedef __bf16 bf16_t;
typedef __bf16 bf16x8 __attribute__((ext_vector_type(8)));
typedef float  f32x4  __attribute__((ext_vector_type(4)));

// ws layout:
//   offs : Bb*NOFF*HW floats  [b][18][hw]
//   xt   : Bb*HW*Cc  floats   [b][hw][c]
//   wtpd : 18*4*64*8 bf16     deform weights, A-fragment order
//   wtpo : 18*2*64*8 bf16     offset-conv weights, A-fragment order
#define OFFS_SZ (Bb*NOFF*HW)
#define XT_SZ   (Bb*HW*Cc)
#define WTPD_SZ (18*4*64*8)
#define WTPO_SZ (18*2*64*8)

// ---------------- x transpose: (b,c,h,w) -> (b,hw,c) ----------------
__global__ void xpose_kernel(const float* __restrict__ x, float* __restrict__ xt) {
    __shared__ float tile[64][65];
    int bid  = blockIdx.x;            // 0..1151
    int b    = bid / 144;
    int t0   = (bid % 144) * 64;
    int lane = threadIdx.x & 63;
    int sub  = threadIdx.x >> 6;
    const float* xb = x + (size_t)b * Cc * HW;
    #pragma unroll
    for (int i = 0; i < 16; ++i) {
        int c = sub * 16 + i;
        tile[c][lane] = xb[c * HW + t0 + lane];
    }
    __syncthreads();
    float* xtb = xt + ((size_t)b * HW + t0) * Cc;
    #pragma unroll
    for (int i = 0; i < 16; ++i) {
        int hw = sub * 16 + i;
        xtb[hw * Cc + lane] = tile[lane][hw];
    }
}

// ---------------- weight prepack: deform conv_w -> A-frag order ----------------
// wtpd[((t*4+mt)*64+l)*8+j] = cw[o][c][k], o = mt*16+(l&15), kidx=t*32+((l>>4)&3)*8+j,
// k = kidx>>6, c = kidx&63   (K-order kidx = k*64 + c)
__global__ void prep_wd(const float* __restrict__ cw, bf16_t* __restrict__ wtpd) {
    int n = blockIdx.x * 256 + threadIdx.x;      // 0..4607
    int t = n >> 8; int rem = n & 255; int mt = rem >> 6; int l = rem & 63;
    int o = mt * 16 + (l & 15);
    int kbase = t * 32 + ((l >> 4) & 3) * 8;
    bf16x8 v;
    #pragma unroll
    for (int j = 0; j < 8; ++j) {
        int kidx = kbase + j; int k = kidx >> 6; int c = kidx & 63;
        v[j] = (bf16_t)cw[(o * 64 + c) * 9 + k];
    }
    *(bf16x8*)&wtpd[n * 8] = v;
}

// offset weights: oc padded 18 -> 32 with zeros
__global__ void prep_wo(const float* __restrict__ ow, bf16_t* __restrict__ wtpo) {
    int n = blockIdx.x * 256 + threadIdx.x;      // 0..2303
    int t = n >> 7; int rem = n & 127; int mt = rem >> 6; int l = rem & 63;
    int oc = mt * 16 + (l & 15);
    int kbase = t * 32 + ((l >> 4) & 3) * 8;
    bf16x8 v;
    #pragma unroll
    for (int j = 0; j < 8; ++j) {
        int kidx = kbase + j; int k = kidx >> 6; int c = kidx & 63;
        v[j] = (oc < NOFF) ? (bf16_t)ow[(oc * 64 + c) * 9 + k] : (bf16_t)0.f;
    }
    *(bf16x8*)&wtpo[n * 8] = v;
}

// ---------------- offset conv via MFMA ----------------
// block = 64 pixels, 4 waves; wave q owns pixels q*16..q*16+15 (barrier-free).
// A = weights [32oc x K], B = staged x-taps [K x 16pix], C[oc][pix].
__global__ __launch_bounds__(256) void offconv_mfma(const float* __restrict__ xt,
        const bf16_t* __restrict__ wtpo, const float* __restrict__ ob,
        float* __restrict__ offs) {
    __shared__ bf16_t Sb[4][16 * 72];
    int bid = blockIdx.x;
    int b = bid / 144, hw0 = (bid % 144) * 64;
    int tid = threadIdx.x, lane = tid & 63, q = tid >> 6;
    int cg = lane & 7, prow = lane >> 3;
    int ph[2], pw[2];
    #pragma unroll
    for (int i = 0; i < 2; ++i) {
        int hw = hw0 + q * 16 + i * 8 + prow;
        ph[i] = hw / 96; pw[i] = hw % 96;
    }
    f32x4 acc[2];
    #pragma unroll
    for (int mt = 0; mt < 2; ++mt)
        #pragma unroll
        for (int r = 0; r < 4; ++r) {
            int oc = mt * 16 + ((lane >> 4) & 3) * 4 + r;
            acc[mt][r] = (oc < NOFF) ? ob[oc] : 0.f;
        }
    bf16_t* myS = &Sb[q][0];
    int bbase = b * HW;
    #pragma unroll
    for (int k = 0; k < 9; ++k) {
        const int ky = k / 3, kx = k % 3;
        #pragma unroll
        for (int i = 0; i < 2; ++i) {
            int y = ph[i] - 1 + ky, x = pw[i] - 1 + kx;
            bool valid = (y >= 0) && (y < Hh) && (x >= 0) && (x < Ww);
            f32x4 ga = {0.f, 0.f, 0.f, 0.f}, gb = {0.f, 0.f, 0.f, 0.f};
            if (valid) {
                const float* p = xt + ((bbase + y * Ww + x) * 64 + cg * 8);
                ga = *(const f32x4*)p;
                gb = *(const f32x4*)(p + 4);
            }
            bf16x8 v;
            #pragma unroll
            for (int j = 0; j < 4; ++j) { v[j] = (bf16_t)ga[j]; v[j + 4] = (bf16_t)gb[j]; }
            *(bf16x8*)&myS[(i * 8 + prow) * 72 + cg * 8] = v;
        }
        #pragma unroll
        for (int s = 0; s < 2; ++s) {
            bf16x8 bfrag = *(bf16x8*)&myS[(lane & 15) * 72 + s * 32 + ((lane >> 4) & 3) * 8];
            int t = k * 2 + s;
            #pragma unroll
            for (int mt = 0; mt < 2; ++mt) {
                bf16x8 afrag = *(const bf16x8*)&wtpo[((t * 2 + mt) * 64 + lane) * 8];
                acc[mt] = __builtin_amdgcn_mfma_f32_16x16x32_bf16(afrag, bfrag, acc[mt], 0, 0, 0);
            }
        }
    }
    #pragma unroll
    for (int mt = 0; mt < 2; ++mt)
        #pragma unroll
        for (int r = 0; r < 4; ++r) {
            int oc = mt * 16 + ((lane >> 4) & 3) * 4 + r;
            if (oc < NOFF)
                offs[(b * NOFF + oc) * HW + hw0 + q * 16 + (lane & 15)] = acc[mt][r];
        }
}

// ---------------- deformable conv via MFMA ----------------
// block = 64 pixels, 4 waves, wave-private staging; per-lane bilinear recompute.
// A = weights [64o x K], B = sampled [K x 16pix], C[o][pix].
__global__ __launch_bounds__(256) void deform_mfma(const float* __restrict__ xt,
        const float* __restrict__ offs, const bf16_t* __restrict__ wtpd,
        const float* __restrict__ cb, float* __restrict__ out) {
    __shared__ float offbuf[64 * 20];            // [pix][18 pad 20] (8B-aligned pairs)
    __shared__ bf16_t Sa[4][16 * 72];
    int bid = blockIdx.x;
    int b = bid / 144, hw0 = (bid % 144) * 64;
    int tid = threadIdx.x, lane = tid & 63, q = tid >> 6;
    {
        int pix = tid & 63, oc0 = tid >> 6;
        #pragma unroll
        for (int r = 0; r < 5; ++r) {
            int oc = oc0 + r * 4;
            if (oc < NOFF)
                offbuf[pix * 20 + oc] = offs[(b * NOFF + oc) * HW + hw0 + pix];
        }
    }
    __syncthreads();
    int cg = lane & 7, prow = lane >> 3;
    int pl[2], ph[2], pw[2];
    #pragma unroll
    for (int i = 0; i < 2; ++i) {
        pl[i] = q * 16 + i * 8 + prow;
        int hw = hw0 + pl[i];
        ph[i] = hw / 96; pw[i] = hw % 96;
    }
    f32x4 acc[4];
    #pragma unroll
    for (int mt = 0; mt < 4; ++mt)
        #pragma unroll
        for (int r = 0; r < 4; ++r)
            acc[mt][r] = cb[mt * 16 + ((lane >> 4) & 3) * 4 + r];
    bf16_t* myS = &Sa[q][0];
    int bbase = b * HW;
    #pragma unroll
    for (int k = 0; k < 9; ++k) {
        const int ky = k / 3, kx = k % 3;
        #pragma unroll
        for (int i = 0; i < 2; ++i) {
            float2 od = *(float2*)&offbuf[pl[i] * 20 + 2 * k];
            float py = (float)(ph[i] - 1 + ky) + od.x;
            float px = (float)(pw[i] - 1 + kx) + od.y;
            float fy = floorf(py), fx = floorf(px);
            float wy = py - fy, wx = px - fx;
            int y0 = (int)fy, x0 = (int)fx;
            int y1 = y0 + 1, x1 = x0 + 1;
            bool vy0 = (unsigned)y0 < (unsigned)Hh, vy1 = (unsigned)y1 < (unsigned)Hh;
            bool vx0 = (unsigned)x0 < (unsigned)Ww, vx1 = (unsigned)x1 < (unsigned)Ww;
            int y0c = min(max(y0, 0), Hh - 1), y1c = min(max(y1, 0), Hh - 1);
            int x0c = min(max(x0, 0), Ww - 1), x1c = min(max(x1, 0), Ww - 1);
            float w00 = (vy0 && vx0) ? (1.f - wy) * (1.f - wx) : 0.f;
            float w01 = (vy0 && vx1) ? (1.f - wy) * wx : 0.f;
            float w10 = (vy1 && vx0) ? wy * (1.f - wx) : 0.f;
            float w11 = (vy1 && vx1) ? wy * wx : 0.f;
            int r0 = (bbase + y0c * Ww) * 64, r1 = (bbase + y1c * Ww) * 64;
            int cb8 = cg * 8;
            const float* p00 = xt + r0 + x0c * 64 + cb8;
            const float* p01 = xt + r0 + x1c * 64 + cb8;
            const float* p10 = xt + r1 + x0c * 64 + cb8;
            const float* p11 = xt + r1 + x1c * 64 + cb8;
            f32x4 va = (*(const f32x4*)p00) * w00 + (*(const f32x4*)p01) * w01
                     + (*(const f32x4*)p10) * w10 + (*(const f32x4*)p11) * w11;
            f32x4 vb = (*(const f32x4*)(p00 + 4)) * w00 + (*(const f32x4*)(p01 + 4)) * w01
                     + (*(const f32x4*)(p10 + 4)) * w10 + (*(const f32x4*)(p11 + 4)) * w11;
            bf16x8 v;
            #pragma unroll
            for (int j = 0; j < 4; ++j) { v[j] = (bf16_t)va[j]; v[j + 4] = (bf16_t)vb[j]; }
            *(bf16x8*)&myS[(i * 8 + prow) * 72 + cb8] = v;
        }
        #pragma unroll
        for (int s = 0; s < 2; ++s) {
            bf16x8 bfrag = *(bf16x8*)&myS[(lane & 15) * 72 + s * 32 + ((lane >> 4) & 3) * 8];
            int t = k * 2 + s;
            #pragma unroll
            for (int mt = 0; mt < 4; ++mt) {
                bf16x8 afrag = *(const bf16x8*)&wtpd[((t * 4 + mt) * 64 + lane) * 8];
                acc[mt] = __builtin_amdgcn_mfma_f32_16x16x32_bf16(afrag, bfrag, acc[mt], 0, 0, 0);
            }
        }
    }
    #pragma unroll
    for (int mt = 0; mt < 4; ++mt)
        #pragma unroll
        for (int r = 0; r < 4; ++r) {
            int o = mt * 16 + ((lane >> 4) & 3) * 4 + r;
            out[(b * Oo + o) * HW + hw0 + q * 16 + (lane & 15)] = acc[mt][r];
        }
}

extern "C" void kernel_launch(void* const* d_in, const int* in_sizes, int n_in,
                              void* d_out, int out_size, void* d_ws, size_t ws_size,
                              hipStream_t stream) {
    const float* x  = (const float*)d_in[0];
    const float* ow = (const float*)d_in[1];
    const float* ob = (const float*)d_in[2];
    const float* cw = (const float*)d_in[3];
    const float* cb = (const float*)d_in[4];
    float* out = (float*)d_out;

    float* offs = (float*)d_ws;
    float* xt   = offs + OFFS_SZ;
    bf16_t* wtpd = (bf16_t*)(xt + XT_SZ);
    bf16_t* wtpo = wtpd + WTPD_SZ;

    xpose_kernel<<<1152, 256, 0, stream>>>(x, xt);
    prep_wd     <<<18,   256, 0, stream>>>(cw, wtpd);
    prep_wo     <<<9,    256, 0, stream>>>(ow, wtpo);
    offconv_mfma<<<1152, 256, 0, stream>>>(xt, wtpo, ob, offs);
    deform_mfma <<<1152, 256, 0, stream>>>(xt, offs, wtpd, cb, out);
}

// Round 4
// 142.672 us; speedup vs baseline: 4.0438x; 1.0830x over previous
//
#include <hip/hip_runtime.h>

#define Bb 8
#define Cc 64
#define Oo 64
#define Hh 96
#define Ww 96
#define HW 9216
#define NOFF 18

typedef __bf16 bf16_t;
typedef __bf16 bf16x8 __attribute__((ext_vector_type(8)));
typedef float  f32x4  __attribute__((ext_vector_type(4)));

// ws layout:
//   offs : Bb*NOFF*HW floats  [b][18][hw]
//   xt   : Bb*HW*Cc  floats   [b][hw][c]
//   wtpd : 18*4*64*8 bf16     deform weights, A-fragment order
//   wtpo : 18*2*64*8 bf16     offset-conv weights, A-fragment order
#define OFFS_SZ (Bb*NOFF*HW)
#define XT_SZ   (Bb*HW*Cc)
#define WTPD_SZ (18*4*64*8)
#define WTPO_SZ (18*2*64*8)

// ---------------- x transpose: (b,c,h,w) -> (b,hw,c) ----------------
__global__ void xpose_kernel(const float* __restrict__ x, float* __restrict__ xt) {
    __shared__ float tile[64][65];
    int bid  = blockIdx.x;            // 0..1151
    int b    = bid / 144;
    int t0   = (bid % 144) * 64;
    int lane = threadIdx.x & 63;
    int sub  = threadIdx.x >> 6;
    const float* xb = x + (size_t)b * Cc * HW;
    #pragma unroll
    for (int i = 0; i < 16; ++i) {
        int c = sub * 16 + i;
        tile[c][lane] = xb[c * HW + t0 + lane];
    }
    __syncthreads();
    float* xtb = xt + ((size_t)b * HW + t0) * Cc;
    #pragma unroll
    for (int i = 0; i < 16; ++i) {
        int hw = sub * 16 + i;
        xtb[hw * Cc + lane] = tile[lane][hw];
    }
}

// ---------------- weight prepack (both sets in one kernel) ----------------
// blocks 0..17  : deform weights  wtpd[((t*4+mt)*64+l)*8+j]
// blocks 18..26 : offset weights  wtpo (oc padded 18->32 with zeros)
__global__ void prep_w(const float* __restrict__ cw, const float* __restrict__ ow,
                       bf16_t* __restrict__ wtpd, bf16_t* __restrict__ wtpo) {
    if (blockIdx.x < 18) {
        int n = blockIdx.x * 256 + threadIdx.x;      // 0..4607
        int t = n >> 8; int rem = n & 255; int mt = rem >> 6; int l = rem & 63;
        int o = mt * 16 + (l & 15);
        int kbase = t * 32 + ((l >> 4) & 3) * 8;
        bf16x8 v;
        #pragma unroll
        for (int j = 0; j < 8; ++j) {
            int kidx = kbase + j; int k = kidx >> 6; int c = kidx & 63;
            v[j] = (bf16_t)cw[(o * 64 + c) * 9 + k];
        }
        *(bf16x8*)&wtpd[n * 8] = v;
    } else {
        int n = (blockIdx.x - 18) * 256 + threadIdx.x;   // 0..2303
        int t = n >> 7; int rem = n & 127; int mt = rem >> 6; int l = rem & 63;
        int oc = mt * 16 + (l & 15);
        int kbase = t * 32 + ((l >> 4) & 3) * 8;
        bf16x8 v;
        #pragma unroll
        for (int j = 0; j < 8; ++j) {
            int kidx = kbase + j; int k = kidx >> 6; int c = kidx & 63;
            v[j] = (oc < NOFF) ? (bf16_t)ow[(oc * 64 + c) * 9 + k] : (bf16_t)0.f;
        }
        *(bf16x8*)&wtpo[n * 8] = v;
    }
}

// ---------------- offset conv via MFMA (software-pipelined staging) ----------------
__global__ __launch_bounds__(256) void offconv_mfma(const float* __restrict__ xt,
        const bf16_t* __restrict__ wtpo, const float* __restrict__ ob,
        float* __restrict__ offs) {
    __shared__ bf16_t Sb[4][16 * 72];
    int bid = blockIdx.x;
    int b = bid / 144, hw0 = (bid % 144) * 64;
    int tid = threadIdx.x, lane = tid & 63, q = tid >> 6;
    int cg = lane & 7, prow = lane >> 3;
    int cb8 = cg * 8;
    int ph[2], pw[2];
    #pragma unroll
    for (int i = 0; i < 2; ++i) {
        int hw = hw0 + q * 16 + i * 8 + prow;
        ph[i] = hw / 96; pw[i] = hw % 96;
    }
    f32x4 acc[2];
    #pragma unroll
    for (int mt = 0; mt < 2; ++mt)
        #pragma unroll
        for (int r = 0; r < 4; ++r) {
            int oc = mt * 16 + ((lane >> 4) & 3) * 4 + r;
            acc[mt][r] = (oc < NOFF) ? ob[oc] : 0.f;
        }
    bf16_t* myS = &Sb[q][0];
    int bbase = b * HW;

    f32x4 g[2][2];
    auto issue = [&](int k, f32x4 (&gg)[2][2]) {
        const int ky = k / 3, kx = k % 3;
        #pragma unroll
        for (int i = 0; i < 2; ++i) {
            int y = ph[i] - 1 + ky, x = pw[i] - 1 + kx;
            bool valid = (y >= 0) && (y < Hh) && (x >= 0) && (x < Ww);
            gg[i][0] = (f32x4){0.f, 0.f, 0.f, 0.f};
            gg[i][1] = (f32x4){0.f, 0.f, 0.f, 0.f};
            if (valid) {
                const float* p = xt + ((bbase + y * Ww + x) * 64 + cb8);
                gg[i][0] = *(const f32x4*)p;
                gg[i][1] = *(const f32x4*)(p + 4);
            }
        }
    };
    issue(0, g);
    #pragma unroll
    for (int k = 0; k < 9; ++k) {
        #pragma unroll
        for (int i = 0; i < 2; ++i) {
            bf16x8 v;
            #pragma unroll
            for (int j = 0; j < 4; ++j) { v[j] = (bf16_t)g[i][0][j]; v[j + 4] = (bf16_t)g[i][1][j]; }
            *(bf16x8*)&myS[(i * 8 + prow) * 72 + cb8] = v;
        }
        if (k < 8) issue(k + 1, g);     // loads fly over the MFMA block below
        #pragma unroll
        for (int s = 0; s < 2; ++s) {
            bf16x8 bfrag = *(bf16x8*)&myS[(lane & 15) * 72 + s * 32 + ((lane >> 4) & 3) * 8];
            int t = k * 2 + s;
            #pragma unroll
            for (int mt = 0; mt < 2; ++mt) {
                bf16x8 afrag = *(const bf16x8*)&wtpo[((t * 2 + mt) * 64 + lane) * 8];
                acc[mt] = __builtin_amdgcn_mfma_f32_16x16x32_bf16(afrag, bfrag, acc[mt], 0, 0, 0);
            }
        }
    }
    #pragma unroll
    for (int mt = 0; mt < 2; ++mt)
        #pragma unroll
        for (int r = 0; r < 4; ++r) {
            int oc = mt * 16 + ((lane >> 4) & 3) * 4 + r;
            if (oc < NOFF)
                offs[(b * NOFF + oc) * HW + hw0 + q * 16 + (lane & 15)] = acc[mt][r];
        }
}

// ---------------- deformable conv via MFMA (software-pipelined gather) ----------------
__global__ __launch_bounds__(256) void deform_mfma(const float* __restrict__ xt,
        const float* __restrict__ offs, const bf16_t* __restrict__ wtpd,
        const float* __restrict__ cb, float* __restrict__ out) {
    __shared__ float offbuf[64 * 20];            // [pix][18 pad 20]
    __shared__ bf16_t Sa[4][16 * 72];
    int bid = blockIdx.x;
    int b = bid / 144, hw0 = (bid % 144) * 64;
    int tid = threadIdx.x, lane = tid & 63, q = tid >> 6;
    {
        int pix = tid & 63, oc0 = tid >> 6;
        #pragma unroll
        for (int r = 0; r < 5; ++r) {
            int oc = oc0 + r * 4;
            if (oc < NOFF)
                offbuf[pix * 20 + oc] = offs[(b * NOFF + oc) * HW + hw0 + pix];
        }
    }
    __syncthreads();
    int cg = lane & 7, prow = lane >> 3;
    int cb8 = cg * 8;
    int pl[2], ph[2], pw[2];
    #pragma unroll
    for (int i = 0; i < 2; ++i) {
        pl[i] = q * 16 + i * 8 + prow;
        int hw = hw0 + pl[i];
        ph[i] = hw / 96; pw[i] = hw % 96;
    }
    f32x4 acc[4];
    #pragma unroll
    for (int mt = 0; mt < 4; ++mt)
        #pragma unroll
        for (int r = 0; r < 4; ++r)
            acc[mt][r] = cb[mt * 16 + ((lane >> 4) & 3) * 4 + r];
    bf16_t* myS = &Sa[q][0];
    int bbase = b * HW;

    f32x4 g[2][8];      // in-flight gather: [i][corner*2+half]
    float w4[2][4];     // bilinear weights for in-flight tap
    auto issue = [&](int k, f32x4 (&gg)[2][8], float (&ww)[2][4]) {
        const int ky = k / 3, kx = k % 3;
        #pragma unroll
        for (int i = 0; i < 2; ++i) {
            float2 od = *(float2*)&offbuf[pl[i] * 20 + 2 * k];
            float py = (float)(ph[i] - 1 + ky) + od.x;
            float px = (float)(pw[i] - 1 + kx) + od.y;
            float fy = floorf(py), fx = floorf(px);
            float wy = py - fy, wx = px - fx;
            int y0 = (int)fy, x0 = (int)fx;
            int y1 = y0 + 1, x1 = x0 + 1;
            bool vy0 = (unsigned)y0 < (unsigned)Hh, vy1 = (unsigned)y1 < (unsigned)Hh;
            bool vx0 = (unsigned)x0 < (unsigned)Ww, vx1 = (unsigned)x1 < (unsigned)Ww;
            int y0c = min(max(y0, 0), Hh - 1), y1c = min(max(y1, 0), Hh - 1);
            int x0c = min(max(x0, 0), Ww - 1), x1c = min(max(x1, 0), Ww - 1);
            ww[i][0] = (vy0 && vx0) ? (1.f - wy) * (1.f - wx) : 0.f;
            ww[i][1] = (vy0 && vx1) ? (1.f - wy) * wx : 0.f;
            ww[i][2] = (vy1 && vx0) ? wy * (1.f - wx) : 0.f;
            ww[i][3] = (vy1 && vx1) ? wy * wx : 0.f;
            int r0 = (bbase + y0c * Ww) * 64, r1 = (bbase + y1c * Ww) * 64;
            const float* p00 = xt + r0 + x0c * 64 + cb8;
            const float* p01 = xt + r0 + x1c * 64 + cb8;
            const float* p10 = xt + r1 + x0c * 64 + cb8;
            const float* p11 = xt + r1 + x1c * 64 + cb8;
            gg[i][0] = *(const f32x4*)p00; gg[i][1] = *(const f32x4*)(p00 + 4);
            gg[i][2] = *(const f32x4*)p01; gg[i][3] = *(const f32x4*)(p01 + 4);
            gg[i][4] = *(const f32x4*)p10; gg[i][5] = *(const f32x4*)(p10 + 4);
            gg[i][6] = *(const f32x4*)p11; gg[i][7] = *(const f32x4*)(p11 + 4);
        }
    };
    issue(0, g, w4);
    #pragma unroll
    for (int k = 0; k < 9; ++k) {
        #pragma unroll
        for (int i = 0; i < 2; ++i) {
            f32x4 va = g[i][0] * w4[i][0] + g[i][2] * w4[i][1]
                     + g[i][4] * w4[i][2] + g[i][6] * w4[i][3];
            f32x4 vb = g[i][1] * w4[i][0] + g[i][3] * w4[i][1]
                     + g[i][5] * w4[i][2] + g[i][7] * w4[i][3];
            bf16x8 v;
            #pragma unroll
            for (int j = 0; j < 4; ++j) { v[j] = (bf16_t)va[j]; v[j + 4] = (bf16_t)vb[j]; }
            *(bf16x8*)&myS[(i * 8 + prow) * 72 + cb8] = v;
        }
        if (k < 8) issue(k + 1, g, w4);   // gather for k+1 flies over MFMA of k
        #pragma unroll
        for (int s = 0; s < 2; ++s) {
            bf16x8 bfrag = *(bf16x8*)&myS[(lane & 15) * 72 + s * 32 + ((lane >> 4) & 3) * 8];
            int t = k * 2 + s;
            #pragma unroll
            for (int mt = 0; mt < 4; ++mt) {
                bf16x8 afrag = *(const bf16x8*)&wtpd[((t * 4 + mt) * 64 + lane) * 8];
                acc[mt] = __builtin_amdgcn_mfma_f32_16x16x32_bf16(afrag, bfrag, acc[mt], 0, 0, 0);
            }
        }
    }
    #pragma unroll
    for (int mt = 0; mt < 4; ++mt)
        #pragma unroll
        for (int r = 0; r < 4; ++r) {
            int o = mt * 16 + ((lane >> 4) & 3) * 4 + r;
            out[(b * Oo + o) * HW + hw0 + q * 16 + (lane & 15)] = acc[mt][r];
        }
}

extern "C" void kernel_launch(void* const* d_in, const int* in_sizes, int n_in,
                              void* d_out, int out_size, void* d_ws, size_t ws_size,
                              hipStream_t stream) {
    const float* x  = (const float*)d_in[0];
    const float* ow = (const float*)d_in[1];
    const float* ob = (const float*)d_in[2];
    const float* cw = (const float*)d_in[3];
    const float* cb = (const float*)d_in[4];
    float* out = (float*)d_out;

    float* offs = (float*)d_ws;
    float* xt   = offs + OFFS_SZ;
    bf16_t* wtpd = (bf16_t*)(xt + XT_SZ);
    bf16_t* wtpo = wtpd + WTPD_SZ;

    xpose_kernel<<<1152, 256, 0, stream>>>(x, xt);
    prep_w      <<<27,   256, 0, stream>>>(cw, ow, wtpd, wtpo);
    offconv_mfma<<<1152, 256, 0, stream>>>(xt, wtpo, ob, offs);
    deform_mfma <<<1152, 256, 0, stream>>>(xt, offs, wtpd, cb, out);
}